// Round 8
// baseline (183.711 us; speedup 1.0000x reference)
//
#include <hip/hip_runtime.h>
#include <hip/hip_bf16.h>

// Data_augV4: out[b] = t1(t0(x[b])), t from samples[(step, b)], 8 transforms.
// prob (d_in[1]) is dead code in the reference.
//
// Round-7 post-mortem: 151us total, our kernels ~33-36us vs ~27us floor; all
// top-5 dispatches are the harness's fixed 47us re-poison fills. Remaining
// slack: the k_reduce2 dispatch (4096-block ramp for ~2 active images).
// Fix: 2 dispatches — fold the double-contrast 2nd reduction into k_apply's
// prologue. Each of the 21 apply blocks of a t0==4&&t1==4 image recomputes
// sum(contrast(x)) over the full image independently (600KB, L3-hot, ~3us,
// deterministic => bit-identical m1 across blocks, no exchange needed);
// hidden under the ~20us apply stream (only ~42 of 2688 blocks affected).
//
//  k_reduce: per-image sum0 = sum(x) partials (32 blocks/img, only if a
//            contrast is involved), fused in the SAME read pass with
//            sum1 = sum(P0(x)) partials for t0 in {3,5,7} (mean-free).
//            t0 in {0,1,2}: mean1 = mean0 (flips preserve mean).
//            t0 == 6     : mean1 = 1 - mean0 (analytic).
//  k_apply : net flips composed into the read address (flips commute with
//            pointwise ops; contrast mean is flip-invariant), pointwise
//            chain P1(P0(v)), nontemporal float4 stores; inline
//            double-contrast mean recompute in the prologue.

#define B_    128
#define C_    3
#define H_    224
#define W_    224
#define N_ELEM (C_*H_*W_)        // 150528 per image
#define N4    (N_ELEM/4)         // 37632 float4 per image
#define W4    (W_/4)             // 56 float4 per row
#define HW4   (H_*W4)            // 12544 float4 per channel
#define S_    32                 // reduce blocks per image
#define CHUNK (N4/S_)            // 1176 float4 per reduce block
#define ABPI  21                 // apply blocks per image (21*256*7 == 37632)
#define APT   7                  // float4 per thread in apply

typedef float f32x4 __attribute__((ext_vector_type(4)));

__device__ __forceinline__ float apply_pw(float v, int tf, float mean) {
    switch (tf) {
        case 3: return fminf(fmaxf(v * 1.5f, 0.0f), 1.0f);                  // brightness
        case 4: return fminf(fmaxf((v - mean) * 1.5f + mean, 0.0f), 1.0f);  // contrast
        case 5: return (v < 0.5f) ? v : (1.0f - v);                         // solarize
        case 6: return 1.0f - v;                                            // invert
        case 7: return floorf(v * 4.0f) * 0.25f;                            // posterize
        default: return v;   // identity / flips (handled via addressing)
    }
}

// Two-value block reduction; result valid in ALL threads.
// Safe to call repeatedly (leading sync). Block-uniform call sites only.
__device__ __forceinline__ float2 block_reduce_sum2(float a, float b) {
    #pragma unroll
    for (int o = 32; o > 0; o >>= 1) {
        a += __shfl_down(a, o, 64);
        b += __shfl_down(b, o, 64);
    }
    __shared__ float2 smem[4];
    const int lane = threadIdx.x & 63, wid = threadIdx.x >> 6;
    __syncthreads();
    if (lane == 0) smem[wid] = make_float2(a, b);
    __syncthreads();
    float2 r;
    r.x = (smem[0].x + smem[1].x) + (smem[2].x + smem[3].x);
    r.y = (smem[0].y + smem[1].y) + (smem[2].y + smem[3].y);
    return r;
}

__global__ __launch_bounds__(256) void k_reduce(const float* __restrict__ x,
                                                const int* __restrict__ samples,
                                                float* __restrict__ ws) {
    const int img = blockIdx.x >> 5, blk = blockIdx.x & 31;
    const int t0 = samples[img], t1 = samples[B_ + img];
    if (!((t0 == 4) || (t1 == 4))) return;      // mean0 never consumed
    const bool need1 = (t1 == 4) && (t0 == 3 || t0 == 5 || t0 == 7);
    float* p0 = ws;                  // B_*S_ floats
    float* p1 = ws + B_ * S_;        // B_*S_ floats
    const float4* xc = (const float4*)x + (size_t)img * N4 + blk * CHUNK;

    float a0 = 0.f, a1 = 0.f;
    for (int i = threadIdx.x; i < CHUNK; i += 256) {
        float4 v = xc[i];
        a0 += (v.x + v.y) + (v.z + v.w);
        if (need1) {
            a1 += apply_pw(v.x, t0, 0.f) + apply_pw(v.y, t0, 0.f)
                + apply_pw(v.z, t0, 0.f) + apply_pw(v.w, t0, 0.f);
        }
    }
    float2 r = block_reduce_sum2(a0, a1);
    if (threadIdx.x == 0) {
        p0[img * S_ + blk] = r.x;
        if (need1) p1[img * S_ + blk] = r.y;
    }
}

__global__ __launch_bounds__(256) void k_apply(const float* __restrict__ x,
                                               const int* __restrict__ samples,
                                               const float* __restrict__ ws,
                                               float* __restrict__ out) {
    const int img = blockIdx.x / ABPI;
    const int t0 = samples[img], t1 = samples[B_ + img];
    const float* p0 = ws;
    const float* p1 = ws + B_ * S_;
    const float4* xi = (const float4*)x + (size_t)img * N4;

    float m0 = 0.f, m1 = 0.f;
    if (t0 == 4 && t1 == 4) {
        // Double contrast (~2 of 128 images): this block recomputes
        // sum(contrast(x)) itself. Deterministic => identical m1 in all 21
        // blocks of the image. Block-uniform branch (sync-safe).
        float s = 0.f;
        #pragma unroll
        for (int i = 0; i < S_; ++i) s += p0[img * S_ + i];   // uniform loads
        m0 = s * (1.0f / N_ELEM);
        float a = 0.f;
        for (int i = threadIdx.x; i < N4; i += 256) {         // L3-hot image
            float4 v = xi[i];
            a += apply_pw(v.x, 4, m0) + apply_pw(v.y, 4, m0)
               + apply_pw(v.z, 4, m0) + apply_pw(v.w, 4, m0);
        }
        float2 r = block_reduce_sum2(a, 0.f);                 // all threads
        m1 = r.x * (1.0f / N_ELEM);
    } else {
        __shared__ float means[2];
        if (threadIdx.x == 0) {
            float a0 = 0.f, a1 = 0.f;
            if (t0 == 4 || t1 == 4) {
                float s = 0.f;
                #pragma unroll
                for (int i = 0; i < S_; ++i) s += p0[img * S_ + i];
                a0 = s * (1.0f / N_ELEM);
            }
            if (t1 == 4) {
                if (t0 < 3)       a1 = a0;        // flips/identity keep mean
                else if (t0 == 6) a1 = 1.0f - a0; // invert: analytic
                else {                            // t0 in {3,5,7}
                    float s = 0.f;
                    #pragma unroll
                    for (int i = 0; i < S_; ++i) s += p1[img * S_ + i];
                    a1 = s * (1.0f / N_ELEM);
                }
            }
            means[0] = a0; means[1] = a1;
        }
        __syncthreads();
        m0 = means[0]; m1 = means[1];
    }

    const bool fw = (t0 == 1) ^ (t1 == 1);      // net flip along W
    const bool fh = (t0 == 2) ^ (t1 == 2);      // net flip along H

    f32x4* oi = (f32x4*)out + (size_t)img * N4;
    const int base = (blockIdx.x % ABPI) * (256 * APT) + threadIdx.x;

    #pragma unroll
    for (int k = 0; k < APT; ++k) {
        const int idx = base + k * 256;         // < N4 by construction
        const int c = idx / HW4, rem = idx % HW4;
        const int h = rem / W4, wq = rem % W4;
        const int hs  = fh ? (H_ - 1 - h)  : h;
        const int wqs = fw ? (W4 - 1 - wq) : wq;
        float4 v = xi[c * HW4 + hs * W4 + wqs];
        if (fw) { float t = v.x; v.x = v.w; v.w = t; t = v.y; v.y = v.z; v.z = t; }
        f32x4 r;
        r.x = apply_pw(apply_pw(v.x, t0, m0), t1, m1);
        r.y = apply_pw(apply_pw(v.y, t0, m0), t1, m1);
        r.z = apply_pw(apply_pw(v.z, t0, m0), t1, m1);
        r.w = apply_pw(apply_pw(v.w, t0, m0), t1, m1);
        __builtin_nontemporal_store(r, &oi[idx]);
    }
}

extern "C" void kernel_launch(void* const* d_in, const int* in_sizes, int n_in,
                              void* d_out, int out_size, void* d_ws, size_t ws_size,
                              hipStream_t stream) {
    const float* x       = (const float*)d_in[0];
    // d_in[1] (prob) is dead code in the reference.
    const int*   samples = (const int*)d_in[2];
    float*       out     = (float*)d_out;
    float*       ws      = (float*)d_ws;        // 2 * B_*S_ floats = 32 KB

    k_reduce<<<B_ * S_,   256, 0, stream>>>(x, samples, ws);
    k_apply <<<B_ * ABPI, 256, 0, stream>>>(x, samples, ws, out);
}

// Round 9
// 151.322 us; speedup vs baseline: 1.2140x; 1.2140x over previous
//
#include <hip/hip_runtime.h>
#include <hip/hip_bf16.h>

// Data_augV4: out[b] = t1(t0(x[b])), t from samples[(step, b)], 8 transforms.
// prob (d_in[1]) is dead code in the reference.
//
// Structure history (measured):
//  - cooperative 1-dispatch: 281us kernel (grid.sync serialization) — NO.
//  - 2-dispatch w/ 1-block double-contrast: 93us serial tail — NO.
//  - 3-dispatch, 32 blocks/img everywhere: 151us total, kernels ~33us — BEST.
//  - 2-dispatch w/ inline double-contrast recompute in apply: 77us straggler
//    blocks (147 latency-bound load rounds/block) — NO. Reverted to BEST.
// Invariant learned: every full-image pass must be spread over >=32 blocks;
// dispatch duration = max over blocks, so rare-case work can't concentrate.
//
//  k_reduce : per-image sum0 = sum(x) partials (32 blocks/img, only if a
//             contrast is involved), fused in the SAME read pass with
//             sum1 = sum(P0(x)) partials for t0 in {3,5,7} (mean-free).
//  k_reduce2: sum1 partials for the rare t0==4 && t1==4 images only
//             (~2 of 128 images); needs m0 from k_reduce. Early-exit else;
//             active blocks do only ~5 load rounds (L3-hot).
//             t0 in {0,1,2}: mean1 = mean0 (flips preserve mean).
//             t0 == 6     : mean1 = 1 - mean0 (analytic).
//  k_apply  : net flips composed into the read address (flips commute with
//             pointwise ops; contrast mean is flip-invariant), pointwise
//             chain P1(P0(v)), nontemporal float4 stores.

#define B_    128
#define C_    3
#define H_    224
#define W_    224
#define N_ELEM (C_*H_*W_)        // 150528 per image
#define N4    (N_ELEM/4)         // 37632 float4 per image
#define W4    (W_/4)             // 56 float4 per row
#define HW4   (H_*W4)            // 12544 float4 per channel
#define S_    32                 // reduce blocks per image
#define CHUNK (N4/S_)            // 1176 float4 per reduce block
#define ABPI  21                 // apply blocks per image (21*256*7 == 37632)
#define APT   7                  // float4 per thread in apply

typedef float f32x4 __attribute__((ext_vector_type(4)));

__device__ __forceinline__ float apply_pw(float v, int tf, float mean) {
    switch (tf) {
        case 3: return fminf(fmaxf(v * 1.5f, 0.0f), 1.0f);                  // brightness
        case 4: return fminf(fmaxf((v - mean) * 1.5f + mean, 0.0f), 1.0f);  // contrast
        case 5: return (v < 0.5f) ? v : (1.0f - v);                         // solarize
        case 6: return 1.0f - v;                                            // invert
        case 7: return floorf(v * 4.0f) * 0.25f;                            // posterize
        default: return v;   // identity / flips (handled via addressing)
    }
}

// Two-value block reduction; safe to call repeatedly (leading sync).
__device__ __forceinline__ float2 block_reduce_sum2(float a, float b) {
    #pragma unroll
    for (int o = 32; o > 0; o >>= 1) {
        a += __shfl_down(a, o, 64);
        b += __shfl_down(b, o, 64);
    }
    __shared__ float2 smem[4];
    const int lane = threadIdx.x & 63, wid = threadIdx.x >> 6;
    __syncthreads();
    if (lane == 0) smem[wid] = make_float2(a, b);
    __syncthreads();
    float2 r;
    r.x = (smem[0].x + smem[1].x) + (smem[2].x + smem[3].x);
    r.y = (smem[0].y + smem[1].y) + (smem[2].y + smem[3].y);
    return r;
}

__global__ __launch_bounds__(256) void k_reduce(const float* __restrict__ x,
                                                const int* __restrict__ samples,
                                                float* __restrict__ ws) {
    const int img = blockIdx.x >> 5, blk = blockIdx.x & 31;
    const int t0 = samples[img], t1 = samples[B_ + img];
    if (!((t0 == 4) || (t1 == 4))) return;      // mean0 never consumed
    const bool need1 = (t1 == 4) && (t0 == 3 || t0 == 5 || t0 == 7);
    float* p0 = ws;                  // B_*S_ floats
    float* p1 = ws + B_ * S_;        // B_*S_ floats
    const float4* xc = (const float4*)x + (size_t)img * N4 + blk * CHUNK;

    float a0 = 0.f, a1 = 0.f;
    for (int i = threadIdx.x; i < CHUNK; i += 256) {
        float4 v = xc[i];
        a0 += (v.x + v.y) + (v.z + v.w);
        if (need1) {
            a1 += apply_pw(v.x, t0, 0.f) + apply_pw(v.y, t0, 0.f)
                + apply_pw(v.z, t0, 0.f) + apply_pw(v.w, t0, 0.f);
        }
    }
    float2 r = block_reduce_sum2(a0, a1);
    if (threadIdx.x == 0) {
        p0[img * S_ + blk] = r.x;
        if (need1) p1[img * S_ + blk] = r.y;
    }
}

// Second pass for double-contrast images only (expected ~2 of 128).
__global__ __launch_bounds__(256) void k_reduce2(const float* __restrict__ x,
                                                 const int* __restrict__ samples,
                                                 float* __restrict__ ws) {
    const int img = blockIdx.x >> 5, blk = blockIdx.x & 31;
    const int t0 = samples[img], t1 = samples[B_ + img];
    if (!(t0 == 4 && t1 == 4)) return;
    const float* p0 = ws;
    float* p1 = ws + B_ * S_;

    float s = 0.f;                               // wave-uniform scalar loads
    #pragma unroll
    for (int i = 0; i < S_; ++i) s += p0[img * S_ + i];
    const float m0 = s * (1.0f / N_ELEM);

    const float4* xc = (const float4*)x + (size_t)img * N4 + blk * CHUNK;
    float a1 = 0.f;
    for (int i = threadIdx.x; i < CHUNK; i += 256) {
        float4 v = xc[i];                        // L2/L3-hot re-read
        a1 += apply_pw(v.x, 4, m0) + apply_pw(v.y, 4, m0)
            + apply_pw(v.z, 4, m0) + apply_pw(v.w, 4, m0);
    }
    float2 r = block_reduce_sum2(a1, 0.f);
    if (threadIdx.x == 0) p1[img * S_ + blk] = r.x;
}

__global__ __launch_bounds__(256) void k_apply(const float* __restrict__ x,
                                               const int* __restrict__ samples,
                                               const float* __restrict__ ws,
                                               float* __restrict__ out) {
    const int img = blockIdx.x / ABPI;
    const int t0 = samples[img], t1 = samples[B_ + img];
    const float* p0 = ws;
    const float* p1 = ws + B_ * S_;

    __shared__ float means[2];
    if (threadIdx.x == 0) {
        float m0 = 0.f, m1 = 0.f;
        if (t0 == 4 || t1 == 4) {
            float s = 0.f;
            #pragma unroll
            for (int i = 0; i < S_; ++i) s += p0[img * S_ + i];
            m0 = s * (1.0f / N_ELEM);
        }
        if (t1 == 4) {
            if (t0 < 3)       m1 = m0;          // flips/identity preserve mean
            else if (t0 == 6) m1 = 1.0f - m0;   // invert: analytic
            else {                              // t0 in {3,4,5,7} reads p1
                float s = 0.f;
                #pragma unroll
                for (int i = 0; i < S_; ++i) s += p1[img * S_ + i];
                m1 = s * (1.0f / N_ELEM);
            }
        }
        means[0] = m0; means[1] = m1;
    }
    __syncthreads();
    const float m0 = means[0], m1 = means[1];

    const bool fw = (t0 == 1) ^ (t1 == 1);      // net flip along W
    const bool fh = (t0 == 2) ^ (t1 == 2);      // net flip along H

    const float4* xi = (const float4*)x + (size_t)img * N4;
    f32x4* oi = (f32x4*)out + (size_t)img * N4;
    const int base = (blockIdx.x % ABPI) * (256 * APT) + threadIdx.x;

    #pragma unroll
    for (int k = 0; k < APT; ++k) {
        const int idx = base + k * 256;         // < N4 by construction
        const int c = idx / HW4, rem = idx % HW4;
        const int h = rem / W4, wq = rem % W4;
        const int hs  = fh ? (H_ - 1 - h)  : h;
        const int wqs = fw ? (W4 - 1 - wq) : wq;
        float4 v = xi[c * HW4 + hs * W4 + wqs];
        if (fw) { float t = v.x; v.x = v.w; v.w = t; t = v.y; v.y = v.z; v.z = t; }
        f32x4 r;
        r.x = apply_pw(apply_pw(v.x, t0, m0), t1, m1);
        r.y = apply_pw(apply_pw(v.y, t0, m0), t1, m1);
        r.z = apply_pw(apply_pw(v.z, t0, m0), t1, m1);
        r.w = apply_pw(apply_pw(v.w, t0, m0), t1, m1);
        __builtin_nontemporal_store(r, &oi[idx]);
    }
}

extern "C" void kernel_launch(void* const* d_in, const int* in_sizes, int n_in,
                              void* d_out, int out_size, void* d_ws, size_t ws_size,
                              hipStream_t stream) {
    const float* x       = (const float*)d_in[0];
    // d_in[1] (prob) is dead code in the reference.
    const int*   samples = (const int*)d_in[2];
    float*       out     = (float*)d_out;
    float*       ws      = (float*)d_ws;        // 2 * B_*S_ floats = 32 KB

    k_reduce <<<B_ * S_,   256, 0, stream>>>(x, samples, ws);
    k_reduce2<<<B_ * S_,   256, 0, stream>>>(x, samples, ws);
    k_apply  <<<B_ * ABPI, 256, 0, stream>>>(x, samples, ws, out);
}